// Round 11
// baseline (434.032 us; speedup 1.0000x reference)
//
#include <hip/hip_runtime.h>

// DeltaModulationEncoder: x (16, 256, 8192) f32 -> spikes {-1,0,1} f32.
// Exact monolithic scan (recurrence serial per channel).
//
// R6/R8 post-mortem: compiler-managed prefetch collapsed in regalloc
// (VGPR 68/72) because plain loads are rematerializable at their uses;
// sched_barrier binds the scheduler, not regalloc.
// R10 post-mortem: raw inline-asm loads are UNSAFE — the compiler may insert
// v_movs between the asm def and the hand-placed waitcnt, reading the dest
// register before the load retires (absmax 2.2 = stale data stored).
//
// Fix with both properties: VOLATILE vector loads.
//   - compiler-visible: SIInsertWaitcnts tracks dest regs and emits exact
//     counted vmcnt before ANY reader (incl. regalloc movs) -> correctness
//     by construction;
//   - non-rematerializable/non-reorderable: regalloc cannot collapse the
//     16-deep pipeline; loads can't sink across the (memory-op) stores.
// Single rotating group q[16] (64 VGPRs pinned), fully unrolled body so all
// indices are compile-time (rule #20). Lookahead = 16 chunks (~1100+ cyc of
// issue+compute) >= HBM latency (~900 cyc). Stores fire-and-forget; waits
// are counted (~vmcnt(31)), never drained in the loop.
// 256 blocks x 1 wave; lanes 0-15 each own one channel (4096 total).

typedef __attribute__((ext_vector_type(4))) float f32x4;

constexpr float TH   = 0.1f;
constexpr int   T    = 8192;
constexpr int   NCH  = 4096;
constexpr int   CPB  = 16;            // channels per block
constexpr int   NBLK = NCH / CPB;     // 256 blocks (one per CU)
constexpr int   NC   = T / 4;         // 2048 float4 chunks per channel
constexpr int   PF   = 16;            // pipeline depth (chunks)

// Bit-exact reference step. Reference: err = x - recon; net = (err>th)-(err<-th);
// recon += net*th; spike = net. net*th is exactly {+0.1f,-0.1f,+0.0f}, so
// recon_next is exactly one of {fl(recon+0.1f), fl(recon-0.1f), recon}
// (recon is never -0.0f, so the net==0 case recon+0.0f == recon bitwise).
// The err = x - recon sub must be kept (comparing x vs fl(recon+TH) is not
// equivalent at rounding boundaries). rp/rm hang OFF the chain; the chain is
// sub -> cmp -> cndmask -> cndmask. No mul feeds an add -> FMA contraction
// cannot change rounding. Spikes selected as inline-constant {-1.0f,0,1.0f}.
__device__ __forceinline__ float dm_step(float xv, float& recon) {
    float rp  = recon + TH;        // off-chain
    float rm  = recon - TH;        // off-chain
    float err = xv - recon;        // chain
    bool  c1  = err > TH;
    bool  c2  = err < -TH;
    float rn  = c1 ? rp : recon;   // chain
    rn        = c2 ? rm : rn;      // chain
    float sp  = c1 ? 1.0f : 0.0f;  // off-chain
    sp        = c2 ? -1.0f : sp;   // off-chain
    recon     = rn;
    return sp;
}

__global__ __launch_bounds__(64, 1) void dm_scan(const float* __restrict__ x,
                                                 float* __restrict__ out) {
    const int lane = threadIdx.x;
    if (lane >= CPB) return;                  // lanes 16-63 idle (exec-masked)
    const int ch = blockIdx.x * CPB + lane;

    const volatile f32x4* __restrict__ vin = (const volatile f32x4*)(x + (size_t)ch * T);
    f32x4*                __restrict__ po  = (f32x4*)(out + (size_t)ch * T);

    // Fill the 16-deep pipeline. Volatile: cannot be remat'd or collapsed.
    f32x4 q[PF];
#pragma unroll
    for (int i = 0; i < PF; ++i) q[i] = vin[i];

    float recon = 0.0f;

    // Main loop: 127 iterations x 16 chunks (chunks 0..2031). Moving pointers
    // so the 16 loads/stores per iteration use constant immediate offsets.
    const volatile f32x4* vld = vin + PF;     // next chunk to load
    f32x4*                pst = po;           // next chunk to store
    for (int it = 0; it < NC / PF - 1; ++it) {
#pragma unroll
        for (int j = 0; j < PF; ++j) {
            f32x4 xv = q[j];                  // compiler waits counted vmcnt here
            q[j] = vld[j];                    // refill: 16 chunks ahead of use
            f32x4 s;
            s.x = dm_step(xv.x, recon);
            s.y = dm_step(xv.y, recon);
            s.z = dm_step(xv.z, recon);
            s.w = dm_step(xv.w, recon);
            pst[j] = s;                       // fire-and-forget
        }
        vld += PF;
        pst += PF;
    }

    // Epilogue: last 16 chunks (2032..2047), no refill.
#pragma unroll
    for (int j = 0; j < PF; ++j) {
        f32x4 xv = q[j];
        f32x4 s;
        s.x = dm_step(xv.x, recon);
        s.y = dm_step(xv.y, recon);
        s.z = dm_step(xv.z, recon);
        s.w = dm_step(xv.w, recon);
        pst[j] = s;
    }
}

extern "C" void kernel_launch(void* const* d_in, const int* in_sizes, int n_in,
                              void* d_out, int out_size, void* d_ws, size_t ws_size,
                              hipStream_t stream) {
    const float* x   = (const float*)d_in[0];
    float*       out = (float*)d_out;
    dm_scan<<<NBLK, 64, 0, stream>>>(x, out);
}

// Round 12
// 203.701 us; speedup vs baseline: 2.1307x; 2.1307x over previous
//
#include <hip/hip_runtime.h>

// DeltaModulationEncoder: x (16, 256, 8192) f32 -> spikes {-1,0,1} f32.
// Exact monolithic scan (recurrence serial per channel).
//
// R6/R8/R10/R11 lesson: HIP source cannot pin a load pipeline (regalloc
// remats loads at uses, or spills volatile results to scratch; raw asm loads
// mixed with compiler movs read stale regs). This round the ENTIRE hot loop
// is hand-written asm over FIXED named registers (clobbers) — the compiler
// never touches pipeline state:
//   v33 = recon, v40 = per-lane byte offset, v48..v50 = step temps,
//   v[64+4j:67+4j]  = q[j], 16-deep chunk pipeline (j = 0..15),
//   v[128+4j:131+4j] = spike set j (rotating: store-source regs are never
//                      overwritten until vmcnt proves the store retired),
//   s8/s9 = +th/-th.
// Per chunk slot: s_waitcnt vmcnt(30)  [exact: my load and my spike-set's
// previous store are both 31 ops old; everything newer stays in flight],
// 4 x 9-instr dm_step, global_store_dwordx4, global_load_dwordx4 (+16 chunks
// ahead). SADDR form: uniform s-pair base + one 32-bit voffset, bumped 256B
// per 16-chunk iteration. 127 load iters + 1 drain + store-only iter.
//
// Step semantics (bit-exact vs reference): err = x - recon (v_sub);
// c1: th < err, c2: -th > err (strict, NaN-false like the reference);
// recon' = c2 ? fl(recon-th) : (c1 ? fl(recon+th) : recon) — identical
// single f32 adds; spike = c2 ? -1.0 : (c1 ? 1.0 : 0.0).
// 256 blocks x 1 wave; lanes 0-15 each own one channel (4096 total).

constexpr int T    = 8192;
constexpr int NCH  = 4096;
constexpr int CPB  = 16;
constexpr int NBLK = NCH / CPB;   // 256

#define STEP(X,S) \
  "v_add_f32 v49, s8, v33\n\t"                  /* rp = th + r   (off-chain) */ \
  "v_subrev_f32 v50, s8, v33\n\t"               /* rm = r - th   (off-chain) */ \
  "v_sub_f32 v48, v" #X ", v33\n\t"             /* err = x - r       (chain) */ \
  "v_cmp_lt_f32 vcc, s8, v48\n\t"               /* c1: th < err      (chain) */ \
  "v_cndmask_b32 v33, v33, v49, vcc\n\t"        /* r = c1 ? rp : r   (chain) */ \
  "v_cndmask_b32 v" #S ", 0, 1.0, vcc\n\t"      /* sp = c1 ? 1 : 0           */ \
  "v_cmp_gt_f32 vcc, s9, v48\n\t"               /* c2: -th > err             */ \
  "v_cndmask_b32 v33, v33, v50, vcc\n\t"        /* r = c2 ? rm : r   (chain) */ \
  "v_cndmask_b32 v" #S ", v" #S ", -1.0, vcc\n\t" /* sp = c2 ? -1 : sp       */

#define SLOT_CLOB(Q0,Q1,Q2,Q3,P0,P1,P2,P3) \
  "vcc","memory","v33","v48","v49","v50", \
  "v" #Q0,"v" #Q1,"v" #Q2,"v" #Q3,"v" #P0,"v" #P1,"v" #P2,"v" #P3

// Steady-state slot: wait(exact) + 4 steps + store(chunk) + load(chunk+16).
#define SLOT(Q0,Q1,Q2,Q3,P0,P1,P2,P3,OFFS,OFFL) asm volatile( \
  "s_waitcnt vmcnt(30)\n\t" \
  STEP(Q0,P0) STEP(Q1,P1) STEP(Q2,P2) STEP(Q3,P3) \
  "global_store_dwordx4 v40, v[" #P0 ":" #P3 "], %1 offset:" #OFFS "\n\t" \
  "global_load_dwordx4 v[" #Q0 ":" #Q3 "], v40, %0 offset:" #OFFL "\n\t" \
  :: "s"(xp), "s"(op) : SLOT_CLOB(Q0,Q1,Q2,Q3,P0,P1,P2,P3))

// Final-iteration slot: everything drained beforehand; no wait, no load.
#define SLOTND(Q0,Q1,Q2,Q3,P0,P1,P2,P3,OFFS) asm volatile( \
  STEP(Q0,P0) STEP(Q1,P1) STEP(Q2,P2) STEP(Q3,P3) \
  "global_store_dwordx4 v40, v[" #P0 ":" #P3 "], %1 offset:" #OFFS "\n\t" \
  :: "s"(xp), "s"(op) : SLOT_CLOB(Q0,Q1,Q2,Q3,P0,P1,P2,P3))

#define ALL_SLOTS(M, ...) \
  M( 64, 65, 66, 67,128,129,130,131,  0 __VA_OPT__(,) __VA_ARGS__(  0)); \
  M( 68, 69, 70, 71,132,133,134,135, 16 __VA_OPT__(,) __VA_ARGS__( 16)); // (unused helper)

__global__ __launch_bounds__(64, 1) void dm_scan(const float* __restrict__ x,
                                                 float* __restrict__ out) {
    const int lane = threadIdx.x;
    if (lane >= CPB) return;                  // exec = 0xFFFF for the rest
    const int ch = blockIdx.x * CPB + lane;

    const float* xp = x;                      // uniform -> "s" (SADDR base)
    float*       op = out;
    unsigned off0 = (unsigned)ch * (unsigned)(T * 4);   // per-lane byte offset

    // Prologue: consts, recon=0, voffset, fill the 16-slot pipeline, drain.
    asm volatile(
        "s_mov_b32 s8, 0x3dcccccd\n\t"        // +0.1f
        "s_mov_b32 s9, 0xbdcccccd\n\t"        // -0.1f
        "v_mov_b32 v33, 0\n\t"
        "v_mov_b32 v40, %2\n\t"
        "global_load_dwordx4 v[64:67],   v40, %0\n\t"
        "global_load_dwordx4 v[68:71],   v40, %0 offset:16\n\t"
        "global_load_dwordx4 v[72:75],   v40, %0 offset:32\n\t"
        "global_load_dwordx4 v[76:79],   v40, %0 offset:48\n\t"
        "global_load_dwordx4 v[80:83],   v40, %0 offset:64\n\t"
        "global_load_dwordx4 v[84:87],   v40, %0 offset:80\n\t"
        "global_load_dwordx4 v[88:91],   v40, %0 offset:96\n\t"
        "global_load_dwordx4 v[92:95],   v40, %0 offset:112\n\t"
        "global_load_dwordx4 v[96:99],   v40, %0 offset:128\n\t"
        "global_load_dwordx4 v[100:103], v40, %0 offset:144\n\t"
        "global_load_dwordx4 v[104:107], v40, %0 offset:160\n\t"
        "global_load_dwordx4 v[108:111], v40, %0 offset:176\n\t"
        "global_load_dwordx4 v[112:115], v40, %0 offset:192\n\t"
        "global_load_dwordx4 v[116:119], v40, %0 offset:208\n\t"
        "global_load_dwordx4 v[120:123], v40, %0 offset:224\n\t"
        "global_load_dwordx4 v[124:127], v40, %0 offset:240\n\t"
        "s_waitcnt vmcnt(0)\n\t"
        :: "s"(xp), "s"(op), "v"(off0)
        : "vcc","memory","s8","s9","v33","v40","v48","v49","v50",
          "v64","v65","v66","v67","v68","v69","v70","v71",
          "v72","v73","v74","v75","v76","v77","v78","v79",
          "v80","v81","v82","v83","v84","v85","v86","v87",
          "v88","v89","v90","v91","v92","v93","v94","v95",
          "v96","v97","v98","v99","v100","v101","v102","v103",
          "v104","v105","v106","v107","v108","v109","v110","v111",
          "v112","v113","v114","v115","v116","v117","v118","v119",
          "v120","v121","v122","v123","v124","v125","v126","v127");

    // 127 iterations x 16 chunks; each slot consumes chunk (16*it + j) and
    // prefetches chunk (16*it + j + 16). Last prefetch: it=126, j=15 ->
    // chunk 2047 (in bounds).
#pragma clang loop unroll(disable)
    for (int it = 0; it < 127; ++it) {
        SLOT( 64, 65, 66, 67, 128,129,130,131,   0, 256);
        SLOT( 68, 69, 70, 71, 132,133,134,135,  16, 272);
        SLOT( 72, 73, 74, 75, 136,137,138,139,  32, 288);
        SLOT( 76, 77, 78, 79, 140,141,142,143,  48, 304);
        SLOT( 80, 81, 82, 83, 144,145,146,147,  64, 320);
        SLOT( 84, 85, 86, 87, 148,149,150,151,  80, 336);
        SLOT( 88, 89, 90, 91, 152,153,154,155,  96, 352);
        SLOT( 92, 93, 94, 95, 156,157,158,159, 112, 368);
        SLOT( 96, 97, 98, 99, 160,161,162,163, 128, 384);
        SLOT(100,101,102,103, 164,165,166,167, 144, 400);
        SLOT(104,105,106,107, 168,169,170,171, 160, 416);
        SLOT(108,109,110,111, 172,173,174,175, 176, 432);
        SLOT(112,113,114,115, 176,177,178,179, 192, 448);
        SLOT(116,117,118,119, 180,181,182,183, 208, 464);
        SLOT(120,121,122,123, 184,185,186,187, 224, 480);
        SLOT(124,125,126,127, 188,189,190,191, 240, 496);
        asm volatile("v_add_u32 v40, 0x100, v40" ::: "v40");
    }

    // Final 16 chunks (2032..2047): drain once, then compute+store only.
    asm volatile("s_waitcnt vmcnt(0)" ::: "memory");
    SLOTND( 64, 65, 66, 67, 128,129,130,131,   0);
    SLOTND( 68, 69, 70, 71, 132,133,134,135,  16);
    SLOTND( 72, 73, 74, 75, 136,137,138,139,  32);
    SLOTND( 76, 77, 78, 79, 140,141,142,143,  48);
    SLOTND( 80, 81, 82, 83, 144,145,146,147,  64);
    SLOTND( 84, 85, 86, 87, 148,149,150,151,  80);
    SLOTND( 88, 89, 90, 91, 152,153,154,155,  96);
    SLOTND( 92, 93, 94, 95, 156,157,158,159, 112);
    SLOTND( 96, 97, 98, 99, 160,161,162,163, 128);
    SLOTND(100,101,102,103, 164,165,166,167, 144);
    SLOTND(104,105,106,107, 168,169,170,171, 160);
    SLOTND(108,109,110,111, 172,173,174,175, 176);
    SLOTND(112,113,114,115, 176,177,178,179, 192);
    SLOTND(116,117,118,119, 180,181,182,183, 208);
    SLOTND(120,121,122,123, 184,185,186,187, 224);
    SLOTND(124,125,126,127, 188,189,190,191, 240);
}

extern "C" void kernel_launch(void* const* d_in, const int* in_sizes, int n_in,
                              void* d_out, int out_size, void* d_ws, size_t ws_size,
                              hipStream_t stream) {
    const float* x   = (const float*)d_in[0];
    float*       out = (float*)d_out;
    dm_scan<<<NBLK, 64, 0, stream>>>(x, out);
}

// Round 13
// 182.688 us; speedup vs baseline: 2.3758x; 1.1150x over previous
//
#include <hip/hip_runtime.h>

// DeltaModulationEncoder: x (16, 256, 8192) f32 -> spikes {-1,0,1} f32.
// Exact monolithic scan (recurrence serial per channel).
//
// R12 (hand-asm 16-deep pipeline, vmcnt(30), 213 us = 62 cyc/step) proved
// loads/stores/waits are off the critical path; the remaining excess over the
// 18-cyc issue floor sits in the step's two v_cmp->v_cndmask pairs (VALU->VALU
// dependencies THROUGH VCC + vcc WAR serialization). This round: branchless
// step, zero vcc/cmp/cndmask — every dependency is VGPR->VGPR forwarding
// (measured ~4 cyc, m07).
//
// Step (8 instr, 5-hop chain), bit-exact vs reference:
//   err = x - recon                        (v_sub)
//   m   = fl(th - |err|)                   (VOP3 sub, abs modifier; sign(m)=1
//                                           iff |err| > th, STRICT at ==th;
//                                           Sterbenz => exact, no -0 edge)
//   mask = m >> 31 (arith)                 (all-ones iff spike)
//   nth  = mask & (sign(err) | 0.1f)       ({+0.1f, -0.1f, +0.0f} exact)
//   recon += nth                           (same single f32 add as reference,
//                                           recon never -0.0f)
//   spike = nth * 10.0f                    (exact: +-0.1f*10 -> +-1.0f, 0->+0)
// Inputs finite (random normal) => no NaN path; reference gives net=0 on NaN
// anyway only for NaN inputs which cannot occur here.
//
// Register map (fixed, compiler never touches):
//   v33 recon | v40 byte-voffset | v46,v47,v48,v49 step temps
//   v[64+4j .. 67+4j]   q[j]  16-deep load pipeline (j=0..15)
//   v[128+4j .. 131+4j] spike set j (rotating: store-source regs only
//                       overwritten after vmcnt proves the store retired)
//   s8 = 0x3dcccccd (+0.1f), s10 = 0x80000000, base pointers in s-pairs.
// Per slot: s_waitcnt vmcnt(30) [exact: my load and this spike-set's previous
// store are both 31 ops old], 4 steps, store(chunk), load(chunk+16).
// 256 blocks x 1 wave; lanes 0-15 each own one channel (4096 total).

constexpr int T    = 8192;
constexpr int NCH  = 4096;
constexpr int CPB  = 16;
constexpr int NBLK = NCH / CPB;   // 256

#define STEP(X,S) \
  "v_sub_f32 v48, v" #X ", v33\n\t"             /* err = x - r      hop1 */ \
  "v_sub_f32_e64 v46, s8, |v48|\n\t"            /* m = th - |err|   hop2 */ \
  "v_and_b32 v47, s10, v48\n\t"                 /* sgn(err)         hop2 */ \
  "v_or_b32 v49, s8, v47\n\t"                   /* +-0.1f           hop3 */ \
  "v_ashrrev_i32 v46, 31, v46\n\t"              /* mask             hop3 */ \
  "v_and_b32 v49, v46, v49\n\t"                 /* nth              hop4 */ \
  "v_add_f32 v33, v33, v49\n\t"                 /* r += nth         hop5 */ \
  "v_mul_f32 v" #S ", 0x41200000, v49\n\t"      /* spike = nth*10   off  */

#define SLOT_CLOB(Q0,Q1,Q2,Q3,P0,P1,P2,P3) \
  "memory","v33","v46","v47","v48","v49", \
  "v" #Q0,"v" #Q1,"v" #Q2,"v" #Q3,"v" #P0,"v" #P1,"v" #P2,"v" #P3

// Steady-state slot: wait(exact) + 4 steps + store(chunk) + load(chunk+16).
#define SLOT(Q0,Q1,Q2,Q3,P0,P1,P2,P3,OFFS,OFFL) asm volatile( \
  "s_waitcnt vmcnt(30)\n\t" \
  STEP(Q0,P0) STEP(Q1,P1) STEP(Q2,P2) STEP(Q3,P3) \
  "global_store_dwordx4 v40, v[" #P0 ":" #P3 "], %1 offset:" #OFFS "\n\t" \
  "global_load_dwordx4 v[" #Q0 ":" #Q3 "], v40, %0 offset:" #OFFL "\n\t" \
  :: "s"(xp), "s"(op) : SLOT_CLOB(Q0,Q1,Q2,Q3,P0,P1,P2,P3))

// Final-iteration slot: everything drained beforehand; no wait, no load.
#define SLOTND(Q0,Q1,Q2,Q3,P0,P1,P2,P3,OFFS) asm volatile( \
  STEP(Q0,P0) STEP(Q1,P1) STEP(Q2,P2) STEP(Q3,P3) \
  "global_store_dwordx4 v40, v[" #P0 ":" #P3 "], %1 offset:" #OFFS "\n\t" \
  :: "s"(xp), "s"(op) : SLOT_CLOB(Q0,Q1,Q2,Q3,P0,P1,P2,P3))

__global__ __launch_bounds__(64, 1) void dm_scan(const float* __restrict__ x,
                                                 float* __restrict__ out) {
    const int lane = threadIdx.x;
    if (lane >= CPB) return;                  // exec = 0xFFFF for the rest
    const int ch = blockIdx.x * CPB + lane;

    const float* xp = x;                      // uniform -> "s" (SADDR base)
    float*       op = out;
    unsigned off0 = (unsigned)ch * (unsigned)(T * 4);   // per-lane byte offset

    // Prologue: consts, recon=0, voffset, fill the 16-slot pipeline, drain.
    asm volatile(
        "s_mov_b32 s8, 0x3dcccccd\n\t"        // +0.1f
        "s_mov_b32 s10, 0x80000000\n\t"       // sign mask
        "v_mov_b32 v33, 0\n\t"
        "v_mov_b32 v40, %2\n\t"
        "global_load_dwordx4 v[64:67],   v40, %0\n\t"
        "global_load_dwordx4 v[68:71],   v40, %0 offset:16\n\t"
        "global_load_dwordx4 v[72:75],   v40, %0 offset:32\n\t"
        "global_load_dwordx4 v[76:79],   v40, %0 offset:48\n\t"
        "global_load_dwordx4 v[80:83],   v40, %0 offset:64\n\t"
        "global_load_dwordx4 v[84:87],   v40, %0 offset:80\n\t"
        "global_load_dwordx4 v[88:91],   v40, %0 offset:96\n\t"
        "global_load_dwordx4 v[92:95],   v40, %0 offset:112\n\t"
        "global_load_dwordx4 v[96:99],   v40, %0 offset:128\n\t"
        "global_load_dwordx4 v[100:103], v40, %0 offset:144\n\t"
        "global_load_dwordx4 v[104:107], v40, %0 offset:160\n\t"
        "global_load_dwordx4 v[108:111], v40, %0 offset:176\n\t"
        "global_load_dwordx4 v[112:115], v40, %0 offset:192\n\t"
        "global_load_dwordx4 v[116:119], v40, %0 offset:208\n\t"
        "global_load_dwordx4 v[120:123], v40, %0 offset:224\n\t"
        "global_load_dwordx4 v[124:127], v40, %0 offset:240\n\t"
        "s_waitcnt vmcnt(0)\n\t"
        :: "s"(xp), "s"(op), "v"(off0)
        : "memory","s8","s10","v33","v40","v46","v47","v48","v49",
          "v64","v65","v66","v67","v68","v69","v70","v71",
          "v72","v73","v74","v75","v76","v77","v78","v79",
          "v80","v81","v82","v83","v84","v85","v86","v87",
          "v88","v89","v90","v91","v92","v93","v94","v95",
          "v96","v97","v98","v99","v100","v101","v102","v103",
          "v104","v105","v106","v107","v108","v109","v110","v111",
          "v112","v113","v114","v115","v116","v117","v118","v119",
          "v120","v121","v122","v123","v124","v125","v126","v127");

    // 127 iterations x 16 chunks; slot j consumes chunk (16*it + j) and
    // prefetches chunk (16*it + j + 16). Last prefetch: it=126, j=15 ->
    // chunk 2047 (in bounds).
#pragma clang loop unroll(disable)
    for (int it = 0; it < 127; ++it) {
        SLOT( 64, 65, 66, 67, 128,129,130,131,   0, 256);
        SLOT( 68, 69, 70, 71, 132,133,134,135,  16, 272);
        SLOT( 72, 73, 74, 75, 136,137,138,139,  32, 288);
        SLOT( 76, 77, 78, 79, 140,141,142,143,  48, 304);
        SLOT( 80, 81, 82, 83, 144,145,146,147,  64, 320);
        SLOT( 84, 85, 86, 87, 148,149,150,151,  80, 336);
        SLOT( 88, 89, 90, 91, 152,153,154,155,  96, 352);
        SLOT( 92, 93, 94, 95, 156,157,158,159, 112, 368);
        SLOT( 96, 97, 98, 99, 160,161,162,163, 128, 384);
        SLOT(100,101,102,103, 164,165,166,167, 144, 400);
        SLOT(104,105,106,107, 168,169,170,171, 160, 416);
        SLOT(108,109,110,111, 172,173,174,175, 176, 432);
        SLOT(112,113,114,115, 176,177,178,179, 192, 448);
        SLOT(116,117,118,119, 180,181,182,183, 208, 464);
        SLOT(120,121,122,123, 184,185,186,187, 224, 480);
        SLOT(124,125,126,127, 188,189,190,191, 240, 496);
        asm volatile("v_add_u32 v40, 0x100, v40" ::: "v40");
    }

    // Final 16 chunks (2032..2047): drain once, then compute+store only.
    asm volatile("s_waitcnt vmcnt(0)" ::: "memory");
    SLOTND( 64, 65, 66, 67, 128,129,130,131,   0);
    SLOTND( 68, 69, 70, 71, 132,133,134,135,  16);
    SLOTND( 72, 73, 74, 75, 136,137,138,139,  32);
    SLOTND( 76, 77, 78, 79, 140,141,142,143,  48);
    SLOTND( 80, 81, 82, 83, 144,145,146,147,  64);
    SLOTND( 84, 85, 86, 87, 148,149,150,151,  80);
    SLOTND( 88, 89, 90, 91, 152,153,154,155,  96);
    SLOTND( 92, 93, 94, 95, 156,157,158,159, 112);
    SLOTND( 96, 97, 98, 99, 160,161,162,163, 128);
    SLOTND(100,101,102,103, 164,165,166,167, 144);
    SLOTND(104,105,106,107, 168,169,170,171, 160);
    SLOTND(108,109,110,111, 172,173,174,175, 176);
    SLOTND(112,113,114,115, 176,177,178,179, 192);
    SLOTND(116,117,118,119, 180,181,182,183, 208);
    SLOTND(120,121,122,123, 184,185,186,187, 224);
    SLOTND(124,125,126,127, 188,189,190,191, 240);
}

extern "C" void kernel_launch(void* const* d_in, const int* in_sizes, int n_in,
                              void* d_out, int out_size, void* d_ws, size_t ws_size,
                              hipStream_t stream) {
    const float* x   = (const float*)d_in[0];
    float*       out = (float*)d_out;
    dm_scan<<<NBLK, 64, 0, stream>>>(x, out);
}